// Round 11
// baseline (195.857 us; speedup 1.0000x reference)
//
#include <hip/hip_runtime.h>
#include <stdint.h>

// Attention fwd B=4,H=16,N=2048,D=64 fp32.
// Round 15: r14 + s_setprio around MFMA clusters — SINGLE-variable test.
// r14 (83 us main, 194.4 total, best): 4-stream waves (64 Q rows), 4-buffer
// LDS staging, 1 barrier/tile, counted vmcnt(8), pins intact.
// Slot model: matrix 2068 + VALU ~2300 vs slot 6225 cyc -> ~29% idle from
// poor pipe overlap; occupancy is structurally capped at 2 waves/SIMD
// (2048 wave-tasks / 1024 SIMDs), so the only overlap lever is scheduler
// arbitration between the 2 resident waves = T5's exact regime (m191 +4-7%).
// r12 bundled setprio with pin-removal and spilled; this round isolates
// setprio with pins/barrier byte-identical to r14. Falsifier: WRITE >> 34 MB
// or VGPR > 128 -> setprio was the r12 culprit, revert.
// Math identical to r14 (absmax 0.00390625).

#define NSEQ 2048
#define DH   64
#define BHN  64
#define NIT  32            // KV tiles of 64 rows

typedef short bf16x8 __attribute__((ext_vector_type(8)));
typedef float f32x4  __attribute__((ext_vector_type(4)));
typedef float f32x16 __attribute__((ext_vector_type(16)));

__device__ __forceinline__ uint16_t f2bf(float x) {
    uint32_t u = __builtin_bit_cast(uint32_t, x);
    return (uint16_t)((u + 0x7fffu + ((u >> 16) & 1u)) >> 16);
}
__device__ __forceinline__ uint32_t pk2(float a, float b) {
    return (uint32_t)f2bf(a) | ((uint32_t)f2bf(b) << 16);
}

// ---------------- prepass: fragment-major K/V gather (r6 version) ----------
// grid 2048 = (bh<<5)|kt, 256 threads. Both K and V staged via LDS with
// coalesced float4 global loads. (Prepass variants measured total-neutral
// across r6/r7/r13/r14 — leave as is.)
__global__ __launch_bounds__(256) void prepass(const float* __restrict__ K,
                                               const float* __restrict__ V,
                                               uint16_t* __restrict__ F) {
    __shared__ float T0[64 * 68];   // K tile [n][d]
    __shared__ float T1[64 * 68];   // V tile [n][d]
    const int b = blockIdx.x, bh = b >> 5, kt = b & 31, t = threadIdx.x;
    const size_t gbase = ((size_t)bh * NSEQ + (size_t)kt * 64) * DH;
    const int n = t >> 2, d0 = (t & 3) * 16;
    #pragma unroll
    for (int i = 0; i < 4; ++i) {
        *(float4*)&T0[n * 68 + d0 + i * 4] = *(const float4*)(K + gbase + n * 64 + d0 + i * 4);
        *(float4*)&T1[n * 68 + d0 + i * 4] = *(const float4*)(V + gbase + n * 64 + d0 + i * 4);
    }
    __syncthreads();
    uint16_t* out = F + (size_t)(bh * 32 + kt) * 8192;
    #pragma unroll
    for (int p = 0; p < 4; ++p) {
        const int e = p * 256 + t, c = e >> 6, l = e & 63;
        const int ll = l & 31, hh = l >> 5;
        float f[8];
        if (c < 8) {            // K A-frag chunk: mtj = c>>2, k2 = c&3
            const int row = (c >> 2) * 32 + ll;
            const int col = hh * 8 + (c & 3) * 16;
            #pragma unroll
            for (int j = 0; j < 8; ++j) f[j] = T0[row * 68 + col + j];
        } else {                // V B-frag chunk: ktg = (c-8)>>1, nd = (c-8)&1
            const int cc = c - 8, ktg = cc >> 1;
            const int d = (cc & 1) * 32 + ll;
            #pragma unroll
            for (int j = 0; j < 8; ++j) {
                const int i = hh * 8 + j;     // 0..15
                const int s = (i & 3) + 8 * ((i >> 2) & 1) + 4 * ((i >> 3) & 1); // pi
                f[j] = T1[(ktg * 16 + s) * 68 + d];
            }
        }
        uint4 o = make_uint4(pk2(f[0], f[1]), pk2(f[2], f[3]),
                             pk2(f[4], f[5]), pk2(f[6], f[7]));
        *(uint4*)(out + (size_t)c * 512 + l * 8) = o;
    }
}

// ---------------- main kernel helpers (all refs -> compile-time regs) ------
__device__ __forceinline__ void load_q(const float* qp, float qscale, bf16x8 (&dst)[4]) {
    #pragma unroll
    for (int k2 = 0; k2 < 4; ++k2) {
        float4 a = *(const float4*)(qp + k2 * 16);
        float4 c = *(const float4*)(qp + k2 * 16 + 4);
        union { uint32_t u[4]; bf16x8 v; } pk;
        pk.u[0] = pk2(a.x * qscale, a.y * qscale);
        pk.u[1] = pk2(a.z * qscale, a.w * qscale);
        pk.u[2] = pk2(c.x * qscale, c.y * qscale);
        pk.u[3] = pk2(c.z * qscale, c.w * qscale);
        dst[k2] = pk.v;
    }
}

// One mtj (32 K rows) for one nt (32 Q rows) of the current KV tile.
// kc = 4 K A-frag chunks for this mtj; vc = 4 V B-frag chunks (j = ktl*2+nd).
// setprio(1) around MFMA clusters (T5); pins at tile boundaries bound
// liveness so setprio cannot extend live ranges across tiles.
__device__ __forceinline__ void tile_mtj(const uint4 (&kc)[4], const uint4 (&vc)[4],
                                         const bf16x8 (&qfn)[4],
                                         f32x16& o0, f32x16& o1, float& lsn) {
    f32x16 s = {};
    __builtin_amdgcn_s_setprio(1);
    #pragma unroll
    for (int k2 = 0; k2 < 4; ++k2)
        s = __builtin_amdgcn_mfma_f32_32x32x16_bf16(
            __builtin_bit_cast(bf16x8, kc[k2]), qfn[k2], s, 0, 0, 0);
    __builtin_amdgcn_s_setprio(0);
    // p = exp2(s); S^T C-regs [8*ktl+jj] are PV A-frag slot order.
    bf16x8 pf0, pf1;
    float g0, g1;
    {
        union { uint32_t u[4]; bf16x8 v; } pp;
        float e[8];
        #pragma unroll
        for (int t2 = 0; t2 < 4; ++t2) {
            e[2 * t2]     = __builtin_amdgcn_exp2f(s[2 * t2]);
            e[2 * t2 + 1] = __builtin_amdgcn_exp2f(s[2 * t2 + 1]);
            pp.u[t2] = __builtin_amdgcn_perm(
                __builtin_bit_cast(uint32_t, e[2 * t2 + 1]),
                __builtin_bit_cast(uint32_t, e[2 * t2]), 0x07060302u);
        }
        g0 = ((e[0] + e[1]) + (e[2] + e[3])) + ((e[4] + e[5]) + (e[6] + e[7]));
        pf0 = pp.v;
    }
    {
        union { uint32_t u[4]; bf16x8 v; } pp;
        float e[8];
        #pragma unroll
        for (int t2 = 0; t2 < 4; ++t2) {
            e[2 * t2]     = __builtin_amdgcn_exp2f(s[8 + 2 * t2]);
            e[2 * t2 + 1] = __builtin_amdgcn_exp2f(s[8 + 2 * t2 + 1]);
            pp.u[t2] = __builtin_amdgcn_perm(
                __builtin_bit_cast(uint32_t, e[2 * t2 + 1]),
                __builtin_bit_cast(uint32_t, e[2 * t2]), 0x07060302u);
        }
        g1 = ((e[0] + e[1]) + (e[2] + e[3])) + ((e[4] + e[5]) + (e[6] + e[7]));
        pf1 = pp.v;
    }
    lsn += g0 + g1;
    __builtin_amdgcn_s_setprio(1);
    o0 = __builtin_amdgcn_mfma_f32_32x32x16_bf16(
        pf0, __builtin_bit_cast(bf16x8, vc[0]), o0, 0, 0, 0);
    o0 = __builtin_amdgcn_mfma_f32_32x32x16_bf16(
        pf1, __builtin_bit_cast(bf16x8, vc[2]), o0, 0, 0, 0);
    o1 = __builtin_amdgcn_mfma_f32_32x32x16_bf16(
        pf0, __builtin_bit_cast(bf16x8, vc[1]), o1, 0, 0, 0);
    o1 = __builtin_amdgcn_mfma_f32_32x32x16_bf16(
        pf1, __builtin_bit_cast(bf16x8, vc[3]), o1, 0, 0, 0);
    __builtin_amdgcn_s_setprio(0);
}

__device__ __forceinline__ void ep_write(float* Ob, int row0,
                                         const f32x16& a0, const f32x16& a1,
                                         float lt, int l31, int h) {
    const float rinv = 1.0f / lt;
    const int rib = __builtin_bit_cast(int, rinv);
    #pragma unroll
    for (int rg = 0; rg < 16; ++rg) {
        const int il = (rg & 3) + 8 * (rg >> 2) + 4 * h;   // C-layout row
        const float inv = __builtin_bit_cast(float,
            __builtin_amdgcn_ds_bpermute(il * 4, rib));
        const int row = row0 + il;
        Ob[(size_t)row * DH + l31]      = a0[rg] * inv;
        Ob[(size_t)row * DH + 32 + l31] = a1[rg] * inv;
    }
}

// Stage this wave's 4 chunks of a 16 KB fragment tile into LDS via DMA.
// LDS dest is wave-uniform base; HW scatters lane i at base + i*16 B, which
// matches the linear chunk layout exactly (read back at sb + c*512 + lane*8).
__device__ __forceinline__ void stage_tile(uint16_t* sb, const uint16_t* ft,
                                           int w, int lane) {
    #pragma unroll
    for (int j = 0; j < 4; ++j) {
        const int c = w * 4 + j;
        __builtin_amdgcn_global_load_lds(
            (const __attribute__((address_space(1))) void*)(ft + (size_t)c * 512 + (size_t)lane * 8),
            (__attribute__((address_space(3))) void*)(sb + c * 512),
            16, 0, 0);
    }
}

// ---------------- main kernel: 4 waves x 64 Q rows each, 4-buffer LDS ------
// Per tile: {stage(kt+2); vmcnt(8); s_barrier; [pin] compute mtj0 then mtj1
// for both nt; [pin]}. One barrier per tile; 2-tile DMA lookahead.
__global__ __launch_bounds__(256, 2) void attn_main(const float* __restrict__ Qg,
                                                    const uint16_t* __restrict__ F,
                                                    float* __restrict__ Og) {
    __shared__ __align__(16) uint16_t SB[4][8192];   // 4 x 16 KB tile buffers
    const int tid = threadIdx.x;
    const int w = tid >> 6, lane = tid & 63;
    const int l31 = lane & 31, h = lane >> 5;
    // XCD-swizzle: blocks with idx%8==r all serve bh in [r*8, r*8+8).
    const int idx = blockIdx.x;                // [0,512)
    const int bh = (idx & 7) * 8 + ((idx >> 3) & 7);
    const int qt = idx >> 6;                   // [0,8): Q rows qt*256..+255

    // Q fragments for this wave's 64 rows (2 nt), pre-scaled into exp2 domain.
    const float qscale = 0.125f * 1.44269504f;
    bf16x8 qf0[4], qf1[4];
    {
        const float* qb = Qg + ((size_t)bh * NSEQ +
                                (size_t)(qt * 256 + w * 64 + l31)) * DH + h * 8;
        load_q(qb, qscale, qf0);
        load_q(qb + 32 * DH, qscale, qf1);
    }

    // Accumulators: named, only compile-time-indexed (rule #20).
    f32x16 oa00 = {}, oa01 = {}, oa10 = {}, oa11 = {};
    float ls0 = 0.0f, ls1 = 0.0f;

    const uint16_t* fbase = F + (size_t)bh * 32 * 8192;

    // prologue: 2-deep prefetch
    stage_tile(&SB[0][0], fbase, w, lane);
    stage_tile(&SB[1][0], fbase + 8192, w, lane);

    #pragma unroll 1
    for (int kt = 0; kt < NIT; ++kt) {
        if (kt + 2 < NIT) {
            stage_tile(&SB[(kt + 2) & 3][0], fbase + (size_t)(kt + 2) * 8192, w, lane);
            asm volatile("s_waitcnt vmcnt(8)" ::: "memory");   // tile kt landed
        } else if (kt + 2 == NIT) {
            asm volatile("s_waitcnt vmcnt(4)" ::: "memory");
        } else {
            asm volatile("s_waitcnt vmcnt(0)" ::: "memory");
        }
        __builtin_amdgcn_s_barrier();           // all waves' tile-kt DMA visible
        __builtin_amdgcn_sched_barrier(0);
        const uint16_t* sb = &SB[kt & 3][0];
        {   // mtj = 0: K rows 0..31
            uint4 kc[4], vc[4];
            #pragma unroll
            for (int c = 0; c < 4; ++c) kc[c] = *(const uint4*)(sb + (c) * 512 + lane * 8);
            #pragma unroll
            for (int c = 0; c < 4; ++c) vc[c] = *(const uint4*)(sb + (8 + c) * 512 + lane * 8);
            tile_mtj(kc, vc, qf0, oa00, oa01, ls0);
            tile_mtj(kc, vc, qf1, oa10, oa11, ls1);
        }
        {   // mtj = 1: K rows 32..63
            uint4 kc[4], vc[4];
            #pragma unroll
            for (int c = 0; c < 4; ++c) kc[c] = *(const uint4*)(sb + (4 + c) * 512 + lane * 8);
            #pragma unroll
            for (int c = 0; c < 4; ++c) vc[c] = *(const uint4*)(sb + (12 + c) * 512 + lane * 8);
            tile_mtj(kc, vc, qf0, oa00, oa01, ls0);
            tile_mtj(kc, vc, qf1, oa10, oa11, ls1);
        }
        __builtin_amdgcn_sched_barrier(0);
    }

    // epilogue: fold lane halves; distribute 1/l via ds_bpermute
    float lt0 = ls0 + __shfl_xor(ls0, 32);
    float lt1 = ls1 + __shfl_xor(ls1, 32);
    float* Ob = Og + (size_t)bh * NSEQ * DH;
    const int row0 = qt * 256 + w * 64;
    ep_write(Ob, row0,      oa00, oa01, lt0, l31, h);
    ep_write(Ob, row0 + 32, oa10, oa11, lt1, l31, h);
}

// ---------------- fallback (round-1 kernel, if ws too small) ----------------
#define LDS_S 72
#define NWAVE 4
#define BN    64
__global__ __launch_bounds__(256) void attn_fwd_fb(const float* __restrict__ Qg,
                                                   const float* __restrict__ Kg,
                                                   const float* __restrict__ Vg,
                                                   float* __restrict__ Og) {
    __shared__ short KsF[BN * LDS_S];
    __shared__ short VtsF[DH * LDS_S];
    __shared__ short PsF[NWAVE * 16 * LDS_S];
    const int tid = threadIdx.x;
    const int wave = tid >> 6, lane = tid & 63, quad = lane >> 4, l16 = lane & 15;
    const int bh = blockIdx.x >> 5, qtf = blockIdx.x & 31;
    const size_t base = (size_t)bh * NSEQ * DH;
    const float* Qb = Qg + base; const float* Kbf = Kg + base;
    const float* Vb = Vg + base; float* Ob = Og + base;
    const float qscale = 0.125f * 1.44269504f;
    bf16x8 qfrag[2];
    {
        const int qrow = qtf * 64 + wave * 16 + l16;
        const float* qp = Qb + (size_t)qrow * DH + quad * 8;
        #pragma unroll
        for (int c = 0; c < 2; ++c) {
            float4 x = *(const float4*)(qp + 32 * c);
            float4 y = *(const float4*)(qp + 32 * c + 4);
            union { uint16_t u[8]; bf16x8 v; } pk;
            pk.u[0]=f2bf(x.x*qscale); pk.u[1]=f2bf(x.y*qscale);
            pk.u[2]=f2bf(x.z*qscale); pk.u[3]=f2bf(x.w*qscale);
            pk.u[4]=f2bf(y.x*qscale); pk.u[5]=f2bf(y.y*qscale);
            pk.u[6]=f2bf(y.z*qscale); pk.u[7]=f2bf(y.w*qscale);
            qfrag[c] = pk.v;
        }
    }
    f32x4 o[4] = {};
    float m_i[4], l_i[4];
    #pragma unroll
    for (int r = 0; r < 4; ++r) { m_i[r] = -1e30f; l_i[r] = 0.0f; }
    const int kr0 = tid >> 4, kd0 = (tid & 15) * 4;
    const int vp = (tid & 31) * 2, vd0 = (tid >> 5) * 8;
    #pragma unroll 1
    for (int kt = 0; kt < NSEQ / BN; ++kt) {
        __syncthreads();
        {
            const float* kbase = Kbf + (size_t)kt * BN * DH;
            #pragma unroll
            for (int jj = 0; jj < 4; ++jj) {
                const int row = kr0 + jj * 16;
                float4 x = *(const float4*)(kbase + (size_t)row * DH + kd0);
                union { uint16_t u[4]; uint64_t ll; } pk;
                pk.u[0]=f2bf(x.x); pk.u[1]=f2bf(x.y); pk.u[2]=f2bf(x.z); pk.u[3]=f2bf(x.w);
                *(uint64_t*)&KsF[row * LDS_S + kd0] = pk.ll;
            }
        }
        {
            const float* v0 = Vb + (size_t)(kt * BN + vp) * DH + vd0;
            const float* v1 = v0 + DH;
            float4 a0 = *(const float4*)(v0); float4 a1 = *(const float4*)(v0 + 4);
            float4 b0 = *(const float4*)(v1); float4 b1 = *(const float4*)(v1 + 4);
            float av[8] = {a0.x,a0.y,a0.z,a0.w,a1.x,a1.y,a1.z,a1.w};
            float bv[8] = {b0.x,b0.y,b0.z,b0.w,b1.x,b1.y,b1.z,b1.w};
            #pragma unroll
            for (int i = 0; i < 8; ++i)
                *(uint32_t*)&VtsF[(vd0 + i) * LDS_S + vp] = pk2(av[i], bv[i]);
        }
        __syncthreads();
        f32x4 s[4] = {};
        #pragma unroll
        for (int c = 0; c < 2; ++c)
            #pragma unroll
            for (int n = 0; n < 4; ++n) {
                bf16x8 kfr = *(const bf16x8*)&KsF[(n * 16 + l16) * LDS_S + quad * 8 + 32 * c];
                s[n] = __builtin_amdgcn_mfma_f32_16x16x32_bf16(qfrag[c], kfr, s[n], 0, 0, 0);
            }
        float rmax[4];
        #pragma unroll
        for (int r = 0; r < 4; ++r)
            rmax[r] = fmaxf(fmaxf(s[0][r], s[1][r]), fmaxf(s[2][r], s[3][r]));
        #pragma unroll
        for (int off = 1; off < 16; off <<= 1)
            #pragma unroll
            for (int r = 0; r < 4; ++r)
                rmax[r] = fmaxf(rmax[r], __shfl_xor(rmax[r], off, 64));
        float alpha[4], rsum[4];
        #pragma unroll
        for (int r = 0; r < 4; ++r) {
            float mn = fmaxf(m_i[r], rmax[r]);
            alpha[r] = __builtin_amdgcn_exp2f(m_i[r] - mn);
            m_i[r] = mn; rsum[r] = 0.0f;
        }
        #pragma unroll
        for (int n = 0; n < 4; ++n)
            #pragma unroll
            for (int r = 0; r < 4; ++r) {
                float p = __builtin_amdgcn_exp2f(s[n][r] - m_i[r]);
                rsum[r] += p;
                PsF[(wave * 16 + quad * 4 + r) * LDS_S + n * 16 + l16] = (short)f2bf(p);
            }
        #pragma unroll
        for (int off = 1; off < 16; off <<= 1)
            #pragma unroll
            for (int r = 0; r < 4; ++r)
                rsum[r] += __shfl_xor(rsum[r], off, 64);
        #pragma unroll
        for (int r = 0; r < 4; ++r) l_i[r] = l_i[r] * alpha[r] + rsum[r];
        #pragma unroll
        for (int n = 0; n < 4; ++n)
            #pragma unroll
            for (int r = 0; r < 4; ++r) o[n][r] *= alpha[r];
        #pragma unroll
        for (int c = 0; c < 2; ++c) {
            bf16x8 pfr = *(const bf16x8*)&PsF[(wave * 16 + l16) * LDS_S + quad * 8 + 32 * c];
            #pragma unroll
            for (int n = 0; n < 4; ++n) {
                bf16x8 vfr = *(const bf16x8*)&VtsF[(n * 16 + l16) * LDS_S + quad * 8 + 32 * c];
                o[n] = __builtin_amdgcn_mfma_f32_16x16x32_bf16(pfr, vfr, o[n], 0, 0, 0);
            }
        }
    }
    float inv[4];
    #pragma unroll
    for (int r = 0; r < 4; ++r) inv[r] = 1.0f / l_i[r];
    const int orow0 = qtf * 64 + wave * 16 + quad * 4;
    #pragma unroll
    for (int n = 0; n < 4; ++n)
        #pragma unroll
        for (int r = 0; r < 4; ++r)
            Ob[(size_t)(orow0 + r) * DH + n * 16 + l16] = o[n][r] * inv[r];
}

extern "C" void kernel_launch(void* const* d_in, const int* in_sizes, int n_in,
                              void* d_out, int out_size, void* d_ws, size_t ws_size,
                              hipStream_t stream) {
    (void)in_sizes; (void)n_in; (void)out_size;
    const float* q = (const float*)d_in[0];
    const float* k = (const float*)d_in[1];
    const float* v = (const float*)d_in[2];
    float* out = (float*)d_out;
    const size_t need = (size_t)BHN * 32 * 16384;   // 33.55 MB fragment buffer
    if (ws_size >= need) {
        uint16_t* fbuf = (uint16_t*)d_ws;
        prepass<<<dim3(BHN * 32), dim3(256), 0, stream>>>(k, v, fbuf);
        attn_main<<<dim3(512), dim3(256), 0, stream>>>(q, fbuf, out);
    } else {
        attn_fwd_fb<<<dim3(BHN * 32), dim3(256), 0, stream>>>(q, k, v, out);
    }
}